// Round 2
// baseline (6584.936 us; speedup 1.0000x reference)
//
#include <hip/hip_runtime.h>

#define NB   32
#define C    64
#define T    512
#define V    25
#define KP   3
#define CO   64
#define H    4
#define DKD  16
#define DVD  16
#define BN_EPS 1e-5f
#define LN_EPS 1e-6f

// ---------------------------------------------------------------------------
// Kernel 1: per-(n,t) fused SCN branch:
//   bn1 -> {partconv + A-aggregation} and {LN -> q/k/v -> attn -> fc + res}
//   -> gated fuse -> bn2 -> relu -> f  (written to workspace, x-layout)
// ---------------------------------------------------------------------------
__global__ __launch_bounds__(256) void scn_kernel(
    const float* __restrict__ x, const float* __restrict__ A,
    const float* __restrict__ bn1_g, const float* __restrict__ bn1_b,
    const float* __restrict__ bn1_m, const float* __restrict__ bn1_v,
    const float* __restrict__ pconv_w, const float* __restrict__ pconv_b,
    const float* __restrict__ wq, const float* __restrict__ wk,
    const float* __restrict__ wv, const float* __restrict__ fc_w,
    const float* __restrict__ ln_g, const float* __restrict__ ln_b,
    const float* __restrict__ gate_w,
    const float* __restrict__ bn2_g, const float* __restrict__ bn2_b,
    const float* __restrict__ bn2_m, const float* __restrict__ bn2_v,
    float* __restrict__ f_out)
{
    const int nt  = blockIdx.x;
    const int n   = nt / T;
    const int t   = nt - n * T;
    const int tid = threadIdx.x;

    __shared__ float s_inp[C][V + 1];        // bn1(x)[c][v]
    __shared__ float s_A[KP][V][V];
    __shared__ float s_pw[KP * CO][V + 1];   // partconv output
    __shared__ float s_agg[C][V + 1];        // after A aggregation
    __shared__ float s_qn[V][C];             // LN'd fa
    __shared__ float s_q[V][C];
    __shared__ float s_k[V][C];
    __shared__ float s_vv[V][C];
    __shared__ float s_att[H][V][V];
    __shared__ float s_xh[V][C];
    __shared__ float s_mu[V], s_rstd[V];

    // ---- load x slice with bn1 applied; load A ----
    for (int i = tid; i < C * V; i += 256) {
        int c = i / V, v = i - c * V;
        float s1 = bn1_g[c] * rsqrtf(bn1_v[c] + BN_EPS);
        float b1 = bn1_b[c] - bn1_m[c] * s1;
        s_inp[c][v] = x[((n * C + c) * T + t) * V + v] * s1 + b1;
    }
    for (int i = tid; i < KP * V * V; i += 256)
        (&s_A[0][0][0])[i] = A[i];
    __syncthreads();

    // ---- pointwise partconv: pw[o][v] = pconv_w[o,:] . inp[:,v] + b[o] ----
    for (int i = tid; i < KP * CO * V; i += 256) {
        int o = i / V, v = i - o * V;
        float acc = pconv_b[o];
        const float* wrow = pconv_w + o * C;
        #pragma unroll 8
        for (int ci = 0; ci < C; ++ci) acc += wrow[ci] * s_inp[ci][v];
        s_pw[o][v] = acc;
    }
    // ---- LN statistics (per joint v over channels) ----
    if (tid < V) {
        float mu = 0.f;
        for (int c = 0; c < C; ++c) mu += s_inp[c][tid];
        mu *= (1.f / C);
        float var = 0.f;
        for (int c = 0; c < C; ++c) { float d = s_inp[c][tid] - mu; var += d * d; }
        var *= (1.f / C);
        s_mu[tid]   = mu;
        s_rstd[tid] = rsqrtf(var + LN_EPS);
    }
    __syncthreads();

    // ---- graph aggregation: agg[c][w] = sum_k sum_v pw[k*CO+c][v]*A[k][v][w] ----
    for (int i = tid; i < CO * V; i += 256) {
        int c = i / V, w = i - c * V;
        float acc = 0.f;
        for (int k = 0; k < KP; ++k) {
            const float* pwr = &s_pw[k * CO + c][0];
            #pragma unroll
            for (int v = 0; v < V; ++v) acc += pwr[v] * s_A[k][v][w];
        }
        s_agg[c][w] = acc;
    }
    // ---- qn = LN(fa) ----
    for (int i = tid; i < V * C; i += 256) {
        int v = i / C, c = i - v * C;
        s_qn[v][c] = (s_inp[c][v] - s_mu[v]) * s_rstd[v] * ln_g[c] + ln_b[c];
    }
    __syncthreads();

    // ---- projections q = qn@wq, k = fa@wk, vv = fa@wv ----
    for (int i = tid; i < 3 * V * C; i += 256) {
        int which = i / (V * C);
        int rem   = i - which * (V * C);
        int v = rem / C, j = rem - v * C;
        float acc = 0.f;
        if (which == 0) {
            #pragma unroll 8
            for (int c = 0; c < C; ++c) acc += s_qn[v][c] * wq[c * C + j];
            s_q[v][j] = acc;
        } else if (which == 1) {
            #pragma unroll 8
            for (int c = 0; c < C; ++c) acc += s_inp[c][v] * wk[c * C + j];
            s_k[v][j] = acc;
        } else {
            #pragma unroll 8
            for (int c = 0; c < C; ++c) acc += s_inp[c][v] * wv[c * C + j];
            s_vv[v][j] = acc;
        }
    }
    __syncthreads();

    // ---- attention scores + softmax (one thread per (h, qv) row) ----
    if (tid < H * V) {
        int h = tid / V, qv = tid - h * V;
        float row[V];
        float mx = -1e30f;
        #pragma unroll
        for (int kv = 0; kv < V; ++kv) {
            float s = 0.f;
            #pragma unroll
            for (int d = 0; d < DKD; ++d)
                s += s_q[qv][h * DKD + d] * s_k[kv][h * DKD + d];
            s *= 0.25f;                      // 1/sqrt(DK)
            row[kv] = s;
            mx = fmaxf(mx, s);
        }
        float sum = 0.f;
        #pragma unroll
        for (int kv = 0; kv < V; ++kv) { float e = __expf(row[kv] - mx); row[kv] = e; sum += e; }
        float inv = 1.f / sum;
        #pragma unroll
        for (int kv = 0; kv < V; ++kv) s_att[h][qv][kv] = row[kv] * inv;
    }
    __syncthreads();

    // ---- xh = att @ vv ----
    for (int i = tid; i < V * C; i += 256) {
        int qv = i / C, j = i - qv * C;
        int h = j / DVD;
        float acc = 0.f;
        #pragma unroll
        for (int kv = 0; kv < V; ++kv) acc += s_att[h][qv][kv] * s_vv[kv][j];
        s_xh[qv][j] = acc;
    }
    __syncthreads();

    // ---- fa_out = xh@fc_w + fa ; fuse with agg ; bn2 ; relu ; store f ----
    const float gate = gate_w[0];
    for (int i = tid; i < C * V; i += 256) {
        int c = i / V, v = i - c * V;
        float acc = 0.f;
        #pragma unroll 8
        for (int d = 0; d < H * DVD; ++d) acc += s_xh[v][d] * fc_w[d * CO + c];
        float fa_out = acc + s_inp[c][v];                 // residual (fa)
        float fv = (fa_out * gate + s_agg[c][v]) * 0.5f;
        float s2 = bn2_g[c] * rsqrtf(bn2_v[c] + BN_EPS);
        float b2 = bn2_b[c] - bn2_m[c] * s2;
        fv = fv * s2 + b2;
        f_out[((n * C + c) * T + t) * V + v] = fmaxf(fv, 0.f);
    }
}

// ---------------------------------------------------------------------------
// Kernel 2: temporal conv (9,1) pad 4 + bias + bn3 + residual relu
// ---------------------------------------------------------------------------
__global__ __launch_bounds__(256) void tcn_kernel(
    const float* __restrict__ f, const float* __restrict__ x,
    const float* __restrict__ tconv_w, const float* __restrict__ tconv_b,
    const float* __restrict__ bn3_g, const float* __restrict__ bn3_b,
    const float* __restrict__ bn3_m, const float* __restrict__ bn3_v,
    float* __restrict__ out)
{
    const int nt  = blockIdx.x;
    const int n   = nt / T;
    const int t   = nt - n * T;
    const int tid = threadIdx.x;

    __shared__ float s_f[C][9][V];   // 57.6 KB: f[n, ci, t-4..t+4, v]

    for (int i = tid; i < C * 9 * V; i += 256) {
        int c   = i / (9 * V);
        int rem = i - c * 9 * V;
        int dt  = rem / V, v = rem - dt * V;
        int tt  = t + dt - 4;
        float val = 0.f;
        if (tt >= 0 && tt < T) val = f[((n * C + c) * T + tt) * V + v];
        s_f[c][dt][v] = val;
    }
    __syncthreads();

    for (int i = tid; i < CO * V; i += 256) {
        int co = i / V, v = i - co * V;
        float acc = tconv_b[co];
        const float* wrow = tconv_w + co * C * 9;
        for (int ci = 0; ci < C; ++ci) {
            #pragma unroll
            for (int dt = 0; dt < 9; ++dt)
                acc += wrow[ci * 9 + dt] * s_f[ci][dt][v];
        }
        float s3 = bn3_g[co] * rsqrtf(bn3_v[co] + BN_EPS);
        float b3 = bn3_b[co] - bn3_m[co] * s3;
        acc = acc * s3 + b3;
        acc += x[((n * C + co) * T + t) * V + v];
        out[((n * C + co) * T + t) * V + v] = fmaxf(acc, 0.f);
    }
}

extern "C" void kernel_launch(void* const* d_in, const int* in_sizes, int n_in,
                              void* d_out, int out_size, void* d_ws, size_t ws_size,
                              hipStream_t stream) {
    const float* x       = (const float*)d_in[0];
    const float* A       = (const float*)d_in[1];
    const float* bn1_g   = (const float*)d_in[2];
    const float* bn1_b   = (const float*)d_in[3];
    const float* bn1_m   = (const float*)d_in[4];
    const float* bn1_v   = (const float*)d_in[5];
    const float* pconv_w = (const float*)d_in[6];
    const float* pconv_b = (const float*)d_in[7];
    const float* wq      = (const float*)d_in[8];
    const float* wk      = (const float*)d_in[9];
    const float* wv      = (const float*)d_in[10];
    const float* fc_w    = (const float*)d_in[11];
    const float* ln_g    = (const float*)d_in[12];
    const float* ln_b    = (const float*)d_in[13];
    const float* gate_w  = (const float*)d_in[14];
    const float* bn2_g   = (const float*)d_in[15];
    const float* bn2_b   = (const float*)d_in[16];
    const float* bn2_m   = (const float*)d_in[17];
    const float* bn2_v   = (const float*)d_in[18];
    const float* tconv_w = (const float*)d_in[19];
    const float* tconv_b = (const float*)d_in[20];
    const float* bn3_g   = (const float*)d_in[21];
    const float* bn3_b   = (const float*)d_in[22];
    const float* bn3_m   = (const float*)d_in[23];
    const float* bn3_v   = (const float*)d_in[24];

    float* f_buf = (float*)d_ws;   // N*C*T*V floats = 104.9 MB
    float* outp  = (float*)d_out;

    dim3 grid(NB * T), block(256);
    scn_kernel<<<grid, block, 0, stream>>>(x, A, bn1_g, bn1_b, bn1_m, bn1_v,
                                           pconv_w, pconv_b, wq, wk, wv, fc_w,
                                           ln_g, ln_b, gate_w,
                                           bn2_g, bn2_b, bn2_m, bn2_v, f_buf);
    tcn_kernel<<<grid, block, 0, stream>>>(f_buf, x, tconv_w, tconv_b,
                                           bn3_g, bn3_b, bn3_m, bn3_v, outp);
}